// Round 1
// baseline (735.023 us; speedup 1.0000x reference)
//
#include <hip/hip_runtime.h>
#include <math.h>

#define B_ 16
#define T_ 2048
#define D_ 512
#define V_ 4096

// ---------------- K1: per-frame argmax + softmax prob of argmax ----------------
// One block (256 threads) per frame. Each thread holds 16 logits (4x float4,
// stride-256 coalesced). p = 1/sum(exp(l - max)) since pred == argmax.
__global__ __launch_bounds__(256) void k_frame(const float* __restrict__ logits,
                                               int* __restrict__ pred,
                                               float* __restrict__ pprob) {
  const int frame = blockIdx.x;
  const float4* row = reinterpret_cast<const float4*>(logits + (size_t)frame * V_);
  const int tid = threadIdx.x;
  float vals[16];
  float vmax = -INFINITY;
  int vidx = 0;
#pragma unroll
  for (int i = 0; i < 4; ++i) {
    float4 x = row[i * 256 + tid];
    const int base = (i * 256 + tid) * 4;
    vals[i * 4 + 0] = x.x; vals[i * 4 + 1] = x.y;
    vals[i * 4 + 2] = x.z; vals[i * 4 + 3] = x.w;
#pragma unroll
    for (int k = 0; k < 4; ++k) {
      float v = vals[i * 4 + k];
      if (v > vmax) { vmax = v; vidx = base + k; }  // strict >: first index wins
    }
  }
  const int lane = tid & 63, wid = tid >> 6;
  // wave-level argmax reduce (wave = 64)
#pragma unroll
  for (int off = 32; off >= 1; off >>= 1) {
    float ov = __shfl_down(vmax, off);
    int   oi = __shfl_down(vidx, off);
    if (ov > vmax || (ov == vmax && oi < vidx)) { vmax = ov; vidx = oi; }
  }
  __shared__ float smax[4];
  __shared__ int   sidx[4];
  __shared__ float ssum[4];
  if (lane == 0) { smax[wid] = vmax; sidx[wid] = vidx; }
  __syncthreads();
  float fm = smax[0]; int fi = sidx[0];
#pragma unroll
  for (int w = 1; w < 4; ++w) {
    if (smax[w] > fm || (smax[w] == fm && sidx[w] < fi)) { fm = smax[w]; fi = sidx[w]; }
  }
  float s = 0.f;
#pragma unroll
  for (int k = 0; k < 16; ++k) s += expf(vals[k] - fm);
#pragma unroll
  for (int off = 32; off >= 1; off >>= 1) s += __shfl_down(s, off);
  if (lane == 0) ssum[wid] = s;
  __syncthreads();
  if (tid == 0) {
    const float tot = ssum[0] + ssum[1] + ssum[2] + ssum[3];
    pred[frame]  = fi;
    pprob[frame] = 1.0f / tot;   // exp(l_pred - max) == 1
  }
}

// ---------------- K2: run-length segmentation per batch ----------------
// One block (256 threads) per batch; 8 frames/thread; block-wide scan of
// start flags -> segment start indices; seg_start[new_len] = L sentinel.
__global__ __launch_bounds__(256) void k_seg(const int* __restrict__ pred,
                                             const int* __restrict__ lengths,
                                             int* __restrict__ seg_start,
                                             int* __restrict__ new_len,
                                             float* __restrict__ out_tail) {
  const int b = blockIdx.x;
  int L = lengths[b];
  L = L < 0 ? 0 : (L > T_ ? T_ : L);
  const int* pr = pred + (size_t)b * T_;
  const int tid = threadIdx.x;
  const int base = tid * 8;
  int f[8];
  int cnt = 0;
#pragma unroll
  for (int j = 0; j < 8; ++j) {
    const int t = base + j;
    const bool st = (t < L) && (t == 0 || pr[t] != pr[t - 1]);
    f[j] = st ? 1 : 0;
    cnt += f[j];
  }
  // inclusive scan of per-thread counts
  const int lane = tid & 63, wid = tid >> 6;
  int inc = cnt;
#pragma unroll
  for (int off = 1; off < 64; off <<= 1) {
    int o = __shfl_up(inc, off);
    if (lane >= off) inc += o;
  }
  __shared__ int wtot[4];
  if (lane == 63) wtot[wid] = inc;
  __syncthreads();
  int excl = inc - cnt;
  for (int w = 0; w < wid; ++w) excl += wtot[w];
  int* ss = seg_start + b * (T_ + 1);
  int seg = excl;
#pragma unroll
  for (int j = 0; j < 8; ++j) {
    if (f[j]) { ss[seg] = base + j; ++seg; }
  }
  if (tid == 0) {
    const int total = wtot[0] + wtot[1] + wtot[2] + wtot[3];
    ss[total] = L;               // sentinel: end of last segment
    new_len[b] = total;
    out_tail[b] = (float)total;  // output 1 (new_lengths) as f32
  }
}

// ---------------- K3: per-segment weighted mean ----------------
// One block (128 threads, float4 each -> D=512) per output row (b,s).
// out = sum(p*h) / (sum(p) + 1e-10); rows s >= new_len write zeros.
__global__ __launch_bounds__(128) void k_out(const float* __restrict__ hidden,
                                             const float* __restrict__ pprob,
                                             const int* __restrict__ seg_start,
                                             const int* __restrict__ new_len,
                                             float* __restrict__ out) {
  const int blk = blockIdx.x;
  const int b = blk >> 11;          // / T_
  const int s = blk & (T_ - 1);
  const int tid = threadIdx.x;
  float4 acc = make_float4(0.f, 0.f, 0.f, 0.f);
  const int nl = new_len[b];
  if (s < nl) {
    const int* ss = seg_start + b * (T_ + 1);
    const int t0 = ss[s], t1 = ss[s + 1];
    const float* pp = pprob + (size_t)b * T_;
    float sp = 0.f;
    for (int t = t0; t < t1; ++t) {
      const float pt = pp[t];
      const float4 h =
          reinterpret_cast<const float4*>(hidden + ((size_t)(b * T_ + t)) * D_)[tid];
      acc.x += pt * h.x; acc.y += pt * h.y;
      acc.z += pt * h.z; acc.w += pt * h.w;
      sp += pt;
    }
    const float inv = 1.0f / (sp + 1e-10f);
    acc.x *= inv; acc.y *= inv; acc.z *= inv; acc.w *= inv;
  }
  reinterpret_cast<float4*>(out)[(size_t)blk * (D_ / 4) + tid] = acc;
}

extern "C" void kernel_launch(void* const* d_in, const int* in_sizes, int n_in,
                              void* d_out, int out_size, void* d_ws, size_t ws_size,
                              hipStream_t stream) {
  const float* hidden  = (const float*)d_in[0];  // (B,T,D) f32
  const float* logits  = (const float*)d_in[1];  // (B,T,V) f32
  const int*   lengths = (const int*)d_in[2];    // (B,) i32
  float* out = (float*)d_out;                    // B*T*D compressed + B new_lengths

  char* ws = (char*)d_ws;
  int*   pred      = (int*)(ws + 0);                       // B*T ints   (128 KB)
  float* pprob     = (float*)(ws + 131072);                // B*T floats (128 KB)
  int*   seg_start = (int*)(ws + 262144);                  // B*(T+1)    (~128 KB)
  int*   new_len   = (int*)(ws + 262144 + B_ * (T_ + 1) * 4);
  float* out_tail  = out + (size_t)B_ * T_ * D_;

  k_frame<<<B_ * T_, 256, 0, stream>>>(logits, pred, pprob);
  k_seg<<<B_, 256, 0, stream>>>(pred, lengths, seg_start, new_len, out_tail);
  k_out<<<B_ * T_, 128, 0, stream>>>(hidden, pprob, seg_start, new_len, out);
}

// Round 2
// 732.270 us; speedup vs baseline: 1.0038x; 1.0038x over previous
//
#include <hip/hip_runtime.h>
#include <math.h>

#define B_ 16
#define T_ 2048
#define D_ 512
#define V_ 4096

// ---------------- K1: per-frame argmax + softmax prob of argmax ----------------
// One block (256 threads) per frame. Each thread holds 16 logits (4x float4,
// stride-256 coalesced). p = 1/sum(exp(l - max)) since pred == argmax.
// __expf (v_exp_f32 fast path) instead of libm expf: ~4x fewer VALU inst.
__global__ __launch_bounds__(256) void k_frame(const float* __restrict__ logits,
                                               int* __restrict__ pred,
                                               float* __restrict__ pprob) {
  const int frame = blockIdx.x;
  const float4* row = reinterpret_cast<const float4*>(logits + (size_t)frame * V_);
  const int tid = threadIdx.x;
  float vals[16];
  float vmax = -INFINITY;
  int vidx = 0;
#pragma unroll
  for (int i = 0; i < 4; ++i) {
    float4 x = row[i * 256 + tid];
    const int base = (i * 256 + tid) * 4;
    vals[i * 4 + 0] = x.x; vals[i * 4 + 1] = x.y;
    vals[i * 4 + 2] = x.z; vals[i * 4 + 3] = x.w;
#pragma unroll
    for (int k = 0; k < 4; ++k) {
      float v = vals[i * 4 + k];
      if (v > vmax) { vmax = v; vidx = base + k; }  // strict >: first index wins
    }
  }
  const int lane = tid & 63, wid = tid >> 6;
  // wave-level argmax reduce (wave = 64)
#pragma unroll
  for (int off = 32; off >= 1; off >>= 1) {
    float ov = __shfl_down(vmax, off);
    int   oi = __shfl_down(vidx, off);
    if (ov > vmax || (ov == vmax && oi < vidx)) { vmax = ov; vidx = oi; }
  }
  __shared__ float smax[4];
  __shared__ int   sidx[4];
  __shared__ float ssum[4];
  if (lane == 0) { smax[wid] = vmax; sidx[wid] = vidx; }
  __syncthreads();
  float fm = smax[0]; int fi = sidx[0];
#pragma unroll
  for (int w = 1; w < 4; ++w) {
    if (smax[w] > fm || (smax[w] == fm && sidx[w] < fi)) { fm = smax[w]; fi = sidx[w]; }
  }
  float s = 0.f;
#pragma unroll
  for (int k = 0; k < 16; ++k) s += __expf(vals[k] - fm);
#pragma unroll
  for (int off = 32; off >= 1; off >>= 1) s += __shfl_down(s, off);
  if (lane == 0) ssum[wid] = s;
  __syncthreads();
  if (tid == 0) {
    const float tot = ssum[0] + ssum[1] + ssum[2] + ssum[3];
    pred[frame]  = fi;
    pprob[frame] = 1.0f / tot;   // exp(l_pred - max) == 1
  }
}

// ---------------- K2: run-length segmentation per batch ----------------
// One block (256 threads) per batch; 8 frames/thread via two int4 loads;
// block-wide scan of start flags -> segment start indices; sentinel at end.
__global__ __launch_bounds__(256) void k_seg(const int* __restrict__ pred,
                                             const int* __restrict__ lengths,
                                             int* __restrict__ seg_start,
                                             int* __restrict__ new_len,
                                             float* __restrict__ out_tail) {
  const int b = blockIdx.x;
  int L = lengths[b];
  L = L < 0 ? 0 : (L > T_ ? T_ : L);
  const int* pr = pred + (size_t)b * T_;
  const int4* pr4 = reinterpret_cast<const int4*>(pr);
  const int tid = threadIdx.x;
  const int base = tid * 8;
  const int4 a = pr4[tid * 2];
  const int4 c = pr4[tid * 2 + 1];
  const int prev = (base > 0) ? pr[base - 1] : -1;
  int v[9] = {prev, a.x, a.y, a.z, a.w, c.x, c.y, c.z, c.w};
  int f[8];
  int cnt = 0;
#pragma unroll
  for (int j = 0; j < 8; ++j) {
    const int t = base + j;
    const bool st = (t < L) && (t == 0 || v[j + 1] != v[j]);
    f[j] = st ? 1 : 0;
    cnt += f[j];
  }
  // inclusive scan of per-thread counts
  const int lane = tid & 63, wid = tid >> 6;
  int inc = cnt;
#pragma unroll
  for (int off = 1; off < 64; off <<= 1) {
    int o = __shfl_up(inc, off);
    if (lane >= off) inc += o;
  }
  __shared__ int wtot[4];
  if (lane == 63) wtot[wid] = inc;
  __syncthreads();
  int excl = inc - cnt;
  for (int w = 0; w < wid; ++w) excl += wtot[w];
  int* ss = seg_start + b * (T_ + 1);
  int seg = excl;
#pragma unroll
  for (int j = 0; j < 8; ++j) {
    if (f[j]) { ss[seg] = base + j; ++seg; }
  }
  if (tid == 0) {
    const int total = wtot[0] + wtot[1] + wtot[2] + wtot[3];
    ss[total] = L;               // sentinel: end of last segment
    new_len[b] = total;
    out_tail[b] = (float)total;  // output 1 (new_lengths) as f32
  }
}

// ---------------- K3: per-segment weighted mean ----------------
// One block (128 threads, float4 each -> D=512) per output row (b,s).
// out = sum(p*h) / (sum(p) + 1e-10); rows s >= new_len write zeros.
__global__ __launch_bounds__(128) void k_out(const float* __restrict__ hidden,
                                             const float* __restrict__ pprob,
                                             const int* __restrict__ seg_start,
                                             const int* __restrict__ new_len,
                                             float* __restrict__ out) {
  const int blk = blockIdx.x;
  const int b = blk >> 11;          // / T_
  const int s = blk & (T_ - 1);
  const int tid = threadIdx.x;
  float4 acc = make_float4(0.f, 0.f, 0.f, 0.f);
  const int nl = new_len[b];
  if (s < nl) {
    const int* ss = seg_start + b * (T_ + 1);
    const int t0 = ss[s], t1 = ss[s + 1];
    const float* pp = pprob + (size_t)b * T_;
    float sp = 0.f;
    for (int t = t0; t < t1; ++t) {
      const float pt = pp[t];
      const float4 h =
          reinterpret_cast<const float4*>(hidden + ((size_t)(b * T_ + t)) * D_)[tid];
      acc.x += pt * h.x; acc.y += pt * h.y;
      acc.z += pt * h.z; acc.w += pt * h.w;
      sp += pt;
    }
    const float inv = 1.0f / (sp + 1e-10f);
    acc.x *= inv; acc.y *= inv; acc.z *= inv; acc.w *= inv;
  }
  reinterpret_cast<float4*>(out)[(size_t)blk * (D_ / 4) + tid] = acc;
}

extern "C" void kernel_launch(void* const* d_in, const int* in_sizes, int n_in,
                              void* d_out, int out_size, void* d_ws, size_t ws_size,
                              hipStream_t stream) {
  const float* hidden  = (const float*)d_in[0];  // (B,T,D) f32
  const float* logits  = (const float*)d_in[1];  // (B,T,V) f32
  const int*   lengths = (const int*)d_in[2];    // (B,) i32
  float* out = (float*)d_out;                    // B*T*D compressed + B new_lengths

  char* ws = (char*)d_ws;
  int*   pred      = (int*)(ws + 0);                       // B*T ints   (128 KB)
  float* pprob     = (float*)(ws + 131072);                // B*T floats (128 KB)
  int*   seg_start = (int*)(ws + 262144);                  // B*(T+1)    (~128 KB)
  int*   new_len   = (int*)(ws + 262144 + B_ * (T_ + 1) * 4);
  float* out_tail  = out + (size_t)B_ * T_ * D_;

  k_frame<<<B_ * T_, 256, 0, stream>>>(logits, pred, pprob);
  k_seg<<<B_, 256, 0, stream>>>(pred, lengths, seg_start, new_len, out_tail);
  k_out<<<B_ * T_, 128, 0, stream>>>(hidden, pprob, seg_start, new_len, out);
}